// Round 6
// baseline (2622.954 us; speedup 1.0000x reference)
//
#include <hip/hip_runtime.h>

#define N_NODES 4096
#define H_DIM 32
#define F_INPUT 5
#define ROLLS 200
#define NBLK 256
#define NBUF 64                          // Mt ring: write-once per 64 steps
#define MT_ELEMS ((size_t)H_DIM * N_NODES)   // 131072 shorts = 256 KiB

typedef __attribute__((ext_vector_type(8))) short bf16x8;
typedef __attribute__((ext_vector_type(4))) float fx4;

__device__ __forceinline__ unsigned short f2bf(float f) {
  unsigned int u = __builtin_bit_cast(unsigned int, f);
  u += 0x7fffu + ((u >> 16) & 1u);   // round-to-nearest-even (inputs are benign, no NaN/inf)
  return (unsigned short)(u >> 16);
}

// consumer side: wave w consumes Mt K-chunk [512w,512w+512) produced by
// blocks 32w..32w+31 — wait on exactly those 32 flags (1/lane, lanes 32-63
// duplicate). No full-grid rendezvous; drift bounded by 1 step (union of
// the 8 groups covers all 256 blocks), ring depth 64 makes reuse safe.
__device__ __forceinline__ void wait_group(const unsigned* flags, int wave,
                                           int lane, unsigned target) {
  const unsigned* f = flags + (wave << 5) + (lane & 31);
  for (;;) {
    unsigned v = __hip_atomic_load(f, __ATOMIC_RELAXED,
                                   __HIP_MEMORY_SCOPE_AGENT);
    if (__ballot(v >= target) == ~0ull) break;
    __builtin_amdgcn_s_sleep(1);
  }
  asm volatile("" ::: "memory");   // keep Mt loads below the wait
}

// Persistent cooperative kernel, async dataflow (per-wave producer waits).
// grid = 256 blocks (1/CU), block = 512 threads (8 waves), 16 rows/block.
// A lives in VGPRs; h/c in LDS; Mt ring-buffered (64) in global.
// Wave 0 alone runs the publish tail (1 KB store + drain + flag) so waves
// 1-7 overlap it with the next step's poll + loads.
__global__ __launch_bounds__(512, 2) void k_roll(
    const float* __restrict__ A, const float* __restrict__ X,
    const float* __restrict__ Wx, const float* __restrict__ Wh, const float* __restrict__ Wc,
    const float* __restrict__ Wih, const float* __restrict__ Whh,
    const float* __restrict__ b_ih, const float* __restrict__ b_hh,
    const float* __restrict__ Wfc, const float* __restrict__ b_fc,
    float* __restrict__ out,
    unsigned short* __restrict__ bufs, unsigned* __restrict__ flags) {

  __shared__ __align__(16) float red[8 * 16 * 33];          // split-K partials (pad 33)
  __shared__ __align__(16) unsigned short inpB[16 * 48];    // inp bf16, A-frag layout
  __shared__ __align__(16) unsigned short hB[16 * 48];      // persistent h (bf16 frag)
  __shared__ __align__(16) unsigned short cnB[16 * 48];     // c_new bf16 (for M_next)
  __shared__ __align__(16) unsigned short MnB[16 * 48];
  __shared__ __align__(16) float cB[16 * 32];               // persistent c (fp32)
  __shared__ __align__(16) float gatesLds[16 * 132];
  __shared__ __align__(16) float xLds[16 * 8];

  const int tid  = threadIdx.x;
  const int wave = tid >> 6;        // 0..7
  const int lane = tid & 63;
  const int l15  = lane & 15;
  const int quad = lane >> 4;       // 0..3
  const int bid  = blockIdx.x;
  const int row0 = bid << 4;

  // ---- prologue: A fragments fp32->bf16 into VGPRs (once) ----
  bf16x8 areg[16];
  {
    const float* Ap = A + (size_t)(row0 + l15) * N_NODES + wave * 512 + quad * 8;
#pragma unroll
    for (int kk = 0; kk < 16; ++kk) {
      bf16x8 a;
#pragma unroll
      for (int j = 0; j < 8; ++j) a[j] = (short)f2bf(Ap[kk * 32 + j]);
      areg[kk] = a;
    }
  }

  // gate weight fragments: wave w owns gate cols [16w, 16w+16)
  const int g = (wave << 4) + l15;
  bf16x8 bI, bH;
#pragma unroll
  for (int j = 0; j < 8; ++j) {
    bI[j] = (short)f2bf(Wih[g * 32 + quad * 8 + j]);
    bH[j] = (short)f2bf(Whh[g * 32 + quad * 8 + j]);
  }
  const float bias = b_ih[g] + b_hh[g];

  // M_next weight fragments (waves 0,1 only): WhT[n][k]=Wh[k][n]
  bf16x8 bWh, bWc;
  float wx5[F_INPUT];
  if (wave < 2) {
#pragma unroll
    for (int j = 0; j < 8; ++j) {
      bWh[j] = (short)f2bf(Wh[(quad * 8 + j) * H_DIM + g]);
      bWc[j] = (short)f2bf(Wc[(quad * 8 + j) * H_DIM + g]);
    }
#pragma unroll
    for (int f = 0; f < F_INPUT; ++f) wx5[f] = Wx[f * H_DIM + g];
  }

  // h = c = 0 ; Mt0 = (x0 @ Wx)^T staged in LDS
  {
    int r = tid >> 5, k = tid & 31;
    hB[r * 48 + k] = 0;       // f2bf(0)==0
    cB[r * 32 + k] = 0.f;
    float s = 0.f;
#pragma unroll
    for (int f = 0; f < F_INPUT; ++f)
      s += X[(size_t)(row0 + r) * F_INPUT + f] * Wx[f * H_DIM + k];
    MnB[r * 48 + k] = f2bf(s);
  }
  __syncthreads();
  if (wave == 0) {             // store Mt0 (1 KB) + publish epoch 1
    int k = lane >> 1, half = lane & 1;
    unsigned* dst = (unsigned*)(bufs + (size_t)k * N_NODES + row0) + half * 4;
#pragma unroll
    for (int j = 0; j < 4; ++j) {
      unsigned lo = MnB[(half * 8 + 2 * j) * 48 + k];
      unsigned hi = MnB[(half * 8 + 2 * j + 1) * 48 + k];
      __hip_atomic_store(dst + j, lo | (hi << 16), __ATOMIC_RELAXED,
                         __HIP_MEMORY_SCOPE_AGENT);
    }
    asm volatile("s_waitcnt vmcnt(0)" ::: "memory");
    if (lane == 0)
      __hip_atomic_store(&flags[bid], 1u, __ATOMIC_RELAXED,
                         __HIP_MEMORY_SCOPE_AGENT);
  }

  for (int t = 0; t < ROLLS; ++t) {
    const unsigned short* m0 = bufs + (size_t)(t & (NBUF - 1)) * MT_ELEMS;
    unsigned short* m1 = bufs + (size_t)((t + 1) & (NBUF - 1)) * MT_ELEMS;

    // window wrap (t = 0,64,128,192): invalidate L1/L2 once so reused ring
    // buffers can't serve stale lines; also clears prior-call lines at t=0
    if ((t & (NBUF - 1)) == 0) {
      __syncthreads();
      if (tid < 64)
        __builtin_amdgcn_fence(__ATOMIC_ACQUIRE, "agent");
      __syncthreads();
    }

    // wait only for THIS wave's 32 producer blocks
    wait_group(flags, wave, lane, (unsigned)(t + 1));

    // stage x_{t+1} early: completes under the MFMAs, clear of any drain.
    // tid<128 = waves 0,1 — the same waves that read xLds in phase E, so
    // write(t) vs read(t-1) is ordered within-wave; no cross-wave hazard.
    if (t + 1 < ROLLS && tid < 128) {
      int r = tid >> 3, f = tid & 7;
      if (f < F_INPUT)
        xLds[r * 8 + f] = X[(size_t)(t + 1) * N_NODES * F_INPUT +
                            (size_t)(row0 + r) * F_INPUT + f];
    }

    // ---- phase A: issue ALL 32 Mt loads first (MLP), then MFMA chain ----
    fx4 acc0 = {0.f, 0.f, 0.f, 0.f}, acc1 = {0.f, 0.f, 0.f, 0.f};
    {
      const unsigned short* B0 = m0 + (size_t)l15 * N_NODES + wave * 512 + quad * 8;
      const unsigned short* B1 = B0 + (size_t)16 * N_NODES;
      bf16x8 s0[16], s1[16];
#pragma unroll
      for (int kk = 0; kk < 16; ++kk) {
        s0[kk] = *(const bf16x8*)(B0 + kk * 32);
        s1[kk] = *(const bf16x8*)(B1 + kk * 32);
      }
#pragma unroll
      for (int kk = 0; kk < 16; ++kk) {
        acc0 = __builtin_amdgcn_mfma_f32_16x16x32_bf16(areg[kk], s0[kk], acc0, 0, 0, 0);
        acc1 = __builtin_amdgcn_mfma_f32_16x16x32_bf16(areg[kk], s1[kk], acc1, 0, 0, 0);
      }
    }
#pragma unroll
    for (int r = 0; r < 4; ++r) {
      red[(wave * 16 + quad * 4 + r) * 33 + l15]      = acc0[r];
      red[(wave * 16 + quad * 4 + r) * 33 + 16 + l15] = acc1[r];
    }
    __syncthreads();

    // ---- phase B: reduce 8 partials -> inp bf16 ----
    {
      int m = tid >> 5, n = tid & 31;
      float s = 0.f;
#pragma unroll
      for (int w = 0; w < 8; ++w) s += red[(w * 16 + m) * 33 + n];
      inpB[m * 48 + n] = f2bf(s);
    }
    __syncthreads();

    // ---- phase C: gates(16x128) = inp@Wih^T + h@Whh^T + b ----
    {
      bf16x8 aI = *(const bf16x8*)(inpB + l15 * 48 + quad * 8);
      bf16x8 aH = *(const bf16x8*)(hB   + l15 * 48 + quad * 8);
      fx4 gacc = {0.f, 0.f, 0.f, 0.f};
      gacc = __builtin_amdgcn_mfma_f32_16x16x32_bf16(aI, bI, gacc, 0, 0, 0);
      gacc = __builtin_amdgcn_mfma_f32_16x16x32_bf16(aH, bH, gacc, 0, 0, 0);
#pragma unroll
      for (int r = 0; r < 4; ++r) gatesLds[(quad * 4 + r) * 132 + g] = gacc[r] + bias;
    }
    __syncthreads();

    // ---- phase D: LSTM cell elementwise (fp32 state in LDS) ----
    {
      int r = tid >> 5, k = tid & 31;
      float gi = gatesLds[r * 132 + k];
      float gf = gatesLds[r * 132 + 32 + k];
      float gg = gatesLds[r * 132 + 64 + k];
      float go = gatesLds[r * 132 + 96 + k];
      float i_ = 1.f / (1.f + __expf(-gi));
      float f_ = 1.f / (1.f + __expf(-gf));
      float g_ = tanhf(gg);
      float o_ = 1.f / (1.f + __expf(-go));
      float cn = f_ * cB[r * 32 + k] + i_ * g_;
      float hn = o_ * tanhf(cn);
      cB[r * 32 + k] = cn;
      hB[r * 48 + k] = f2bf(hn);        // next step's h fragment
      cnB[r * 48 + k] = f2bf(cn);
      if (t == ROLLS - 1) gatesLds[r * 132 + k] = hn * Wfc[k];
    }
    __syncthreads();

    // ---- phase E: M_next = h@Wh + c@Wc + x@Wx (waves 0,1) ----
    if (t < ROLLS - 1) {
      if (wave < 2) {
        bf16x8 aH = *(const bf16x8*)(hB  + l15 * 48 + quad * 8);
        bf16x8 aC = *(const bf16x8*)(cnB + l15 * 48 + quad * 8);
        fx4 m4 = {0.f, 0.f, 0.f, 0.f};
        m4 = __builtin_amdgcn_mfma_f32_16x16x32_bf16(aH, bWh, m4, 0, 0, 0);
        m4 = __builtin_amdgcn_mfma_f32_16x16x32_bf16(aC, bWc, m4, 0, 0, 0);
#pragma unroll
        for (int r = 0; r < 4; ++r) {
          int m = quad * 4 + r;
          float xs = m4[r];
#pragma unroll
          for (int f = 0; f < F_INPUT; ++f) xs += xLds[m * 8 + f] * wx5[f];
          MnB[m * 48 + g] = f2bf(xs);
        }
      }
      __syncthreads();                 // MnB ready — waves 1-7 fall through to t+1
      if (wave == 0) {                 // publish tail: 1 KB store + drain + flag
        int k = lane >> 1, half = lane & 1;
        unsigned* dst = (unsigned*)(m1 + (size_t)k * N_NODES + row0) + half * 4;
#pragma unroll
        for (int j = 0; j < 4; ++j) {
          unsigned lo = MnB[(half * 8 + 2 * j) * 48 + k];
          unsigned hi = MnB[(half * 8 + 2 * j + 1) * 48 + k];
          __hip_atomic_store(dst + j, lo | (hi << 16), __ATOMIC_RELAXED,
                             __HIP_MEMORY_SCOPE_AGENT);
        }
        asm volatile("s_waitcnt vmcnt(0)" ::: "memory");
        if (lane == 0)
          __hip_atomic_store(&flags[bid], (unsigned)(t + 2), __ATOMIC_RELAXED,
                             __HIP_MEMORY_SCOPE_AGENT);
      }
    }
  }

  // ---- epilogue: out = h_final @ Wfc^T + b_fc ----
  if (tid < 16) {
    float s = b_fc[0];
#pragma unroll
    for (int k = 0; k < 32; ++k) s += gatesLds[tid * 132 + k];
    out[row0 + tid] = s;
  }
}

extern "C" void kernel_launch(void* const* d_in, const int* in_sizes, int n_in,
                              void* d_out, int out_size, void* d_ws, size_t ws_size,
                              hipStream_t stream) {
  (void)in_sizes; (void)n_in; (void)out_size; (void)ws_size;
  const float* X   = (const float*)d_in[0];
  const float* A   = (const float*)d_in[1];
  const float* Wx  = (const float*)d_in[2];
  const float* Wh  = (const float*)d_in[3];
  const float* Wc  = (const float*)d_in[4];
  const float* Wih = (const float*)d_in[5];
  const float* Whh = (const float*)d_in[6];
  const float* bih = (const float*)d_in[7];
  const float* bhh = (const float*)d_in[8];
  const float* Wfc = (const float*)d_in[9];
  const float* bfc = (const float*)d_in[10];
  float* outp = (float*)d_out;

  char* ws = (char*)d_ws;
  unsigned short* bufs = (unsigned short*)ws;
  ws += (size_t)NBUF * MT_ELEMS * 2;           // 16 MiB Mt ring
  unsigned* flags = (unsigned*)ws;
  ws += NBLK * sizeof(unsigned);

  // epoch flags must start at 0 every call (graph-capturable async memset)
  (void)hipMemsetAsync(flags, 0, NBLK * sizeof(unsigned), stream);

  void* args[] = {
    (void*)&A, (void*)&X, (void*)&Wx, (void*)&Wh, (void*)&Wc,
    (void*)&Wih, (void*)&Whh, (void*)&bih, (void*)&bhh,
    (void*)&Wfc, (void*)&bfc, (void*)&outp,
    (void*)&bufs, (void*)&flags
  };
  (void)hipLaunchCooperativeKernel((const void*)k_roll, dim3(NBLK), dim3(512),
                                   args, 0, stream);
}

// Round 7
// 2606.885 us; speedup vs baseline: 1.0062x; 1.0062x over previous
//
#include <hip/hip_runtime.h>

#define N_NODES 4096
#define H_DIM 32
#define F_INPUT 5
#define ROLLS 200
#define NBLK 256
#define NBUF 64                          // Mt ring: write-once per 64 steps
#define MT_ELEMS ((size_t)H_DIM * N_NODES)   // 131072 shorts = 256 KiB

typedef __attribute__((ext_vector_type(8))) short bf16x8;
typedef __attribute__((ext_vector_type(4))) float fx4;

__device__ __forceinline__ unsigned short f2bf(float f) {
  unsigned int u = __builtin_bit_cast(unsigned int, f);
  u += 0x7fffu + ((u >> 16) & 1u);   // round-to-nearest-even (inputs are benign, no NaN/inf)
  return (unsigned short)(u >> 16);
}

// consumer side: wave w consumes Mt K-chunk [512w,512w+512) produced by
// blocks 32w..32w+31 — wait on exactly those 32 flags (1/lane, lanes 32-63
// duplicate). Drift bounded by 1 step; ring depth 64 makes reuse safe.
__device__ __forceinline__ void wait_group(const unsigned* flags, int wave,
                                           int lane, unsigned target) {
  const unsigned* f = flags + (wave << 5) + (lane & 31);
  for (;;) {
    unsigned v = __hip_atomic_load(f, __ATOMIC_RELAXED,
                                   __HIP_MEMORY_SCOPE_AGENT);
    if (__ballot(v >= target) == ~0ull) break;
    __builtin_amdgcn_s_sleep(1);
  }
  asm volatile("" ::: "memory");   // keep Mt loads below the wait
}

// Persistent cooperative kernel, async dataflow + rotated K-chunk order.
// grid = 256 blocks (1/CU), block = 512 threads (8 waves), 16 rows/block.
// A lives in VGPRs (rotated chunk order); h/c in LDS; Mt ring (64) global.
// Rotation de-duplicates concurrent same-line L3 misses across the 32
// blocks of an XCD: first toucher fills L2, siblings hit L2.
__global__ __launch_bounds__(512, 2) void k_roll(
    const float* __restrict__ A, const float* __restrict__ X,
    const float* __restrict__ Wx, const float* __restrict__ Wh, const float* __restrict__ Wc,
    const float* __restrict__ Wih, const float* __restrict__ Whh,
    const float* __restrict__ b_ih, const float* __restrict__ b_hh,
    const float* __restrict__ Wfc, const float* __restrict__ b_fc,
    float* __restrict__ out,
    unsigned short* __restrict__ bufs, unsigned* __restrict__ flags) {

  __shared__ __align__(16) float red[8 * 16 * 33];          // split-K partials (pad 33)
  __shared__ __align__(16) unsigned short inpB[16 * 48];    // inp bf16, A-frag layout
  __shared__ __align__(16) unsigned short hB[16 * 48];      // persistent h (bf16 frag)
  __shared__ __align__(16) unsigned short cnB[16 * 48];     // c_new bf16 (for M_next)
  __shared__ __align__(16) unsigned short MnB[16 * 48];
  __shared__ __align__(16) float cB[16 * 32];               // persistent c (fp32)
  __shared__ __align__(16) float gatesLds[16 * 132];
  __shared__ __align__(16) float xLds[16 * 8];

  const int tid  = threadIdx.x;
  const int wave = tid >> 6;        // 0..7
  const int lane = tid & 63;
  const int l15  = lane & 15;
  const int quad = lane >> 4;       // 0..3
  const int bid  = blockIdx.x;
  const int row0 = bid << 4;
  // per-block K-chunk rotation: distinct for same-XCD blocks under both
  // round-robin (xcd=bid%8) and chunked (xcd=bid/32) mappings
  const int rot = ((bid >> 3) ^ ((bid & 7) << 2)) & 15;

  // ---- prologue: A fragments fp32->bf16 into VGPRs, ROTATED chunk order:
  // areg[s] holds K-chunk (s+rot)&15 so MFMA pairing stays static-indexed.
  bf16x8 areg[16];
  {
    const float* Ap = A + (size_t)(row0 + l15) * N_NODES + wave * 512 + quad * 8;
#pragma unroll
    for (int s = 0; s < 16; ++s) {
      int kkr = (s + rot) & 15;
      bf16x8 a;
#pragma unroll
      for (int j = 0; j < 8; ++j) a[j] = (short)f2bf(Ap[kkr * 32 + j]);
      areg[s] = a;
    }
  }

  // gate weight fragments: wave w owns gate cols [16w, 16w+16)
  const int g = (wave << 4) + l15;
  bf16x8 bI, bH;
#pragma unroll
  for (int j = 0; j < 8; ++j) {
    bI[j] = (short)f2bf(Wih[g * 32 + quad * 8 + j]);
    bH[j] = (short)f2bf(Whh[g * 32 + quad * 8 + j]);
  }
  const float bias = b_ih[g] + b_hh[g];

  // M_next weight fragments (waves 0,1 only): WhT[n][k]=Wh[k][n]
  bf16x8 bWh, bWc;
  float wx5[F_INPUT];
  if (wave < 2) {
#pragma unroll
    for (int j = 0; j < 8; ++j) {
      bWh[j] = (short)f2bf(Wh[(quad * 8 + j) * H_DIM + g]);
      bWc[j] = (short)f2bf(Wc[(quad * 8 + j) * H_DIM + g]);
    }
#pragma unroll
    for (int f = 0; f < F_INPUT; ++f) wx5[f] = Wx[f * H_DIM + g];
  }

  // h = c = 0 ; Mt0 = (x0 @ Wx)^T staged in LDS
  {
    int r = tid >> 5, k = tid & 31;
    hB[r * 48 + k] = 0;       // f2bf(0)==0
    cB[r * 32 + k] = 0.f;
    float s = 0.f;
#pragma unroll
    for (int f = 0; f < F_INPUT; ++f)
      s += X[(size_t)(row0 + r) * F_INPUT + f] * Wx[f * H_DIM + k];
    MnB[r * 48 + k] = f2bf(s);
  }
  __syncthreads();
  if (wave == 0) {             // store Mt0 (1 KB) + publish epoch 1
    int k = lane >> 1, half = lane & 1;
    unsigned* dst = (unsigned*)(bufs + (size_t)k * N_NODES + row0) + half * 4;
#pragma unroll
    for (int j = 0; j < 4; ++j) {
      unsigned lo = MnB[(half * 8 + 2 * j) * 48 + k];
      unsigned hi = MnB[(half * 8 + 2 * j + 1) * 48 + k];
      __hip_atomic_store(dst + j, lo | (hi << 16), __ATOMIC_RELAXED,
                         __HIP_MEMORY_SCOPE_AGENT);
    }
    asm volatile("s_waitcnt vmcnt(0)" ::: "memory");
    if (lane == 0)
      __hip_atomic_store(&flags[bid], 1u, __ATOMIC_RELAXED,
                         __HIP_MEMORY_SCOPE_AGENT);
  }

  for (int t = 0; t < ROLLS; ++t) {
    const unsigned short* m0 = bufs + (size_t)(t & (NBUF - 1)) * MT_ELEMS;
    unsigned short* m1 = bufs + (size_t)((t + 1) & (NBUF - 1)) * MT_ELEMS;

    // window wrap (t = 0,64,128,192): invalidate L1/L2 once so reused ring
    // buffers can't serve stale lines; also clears prior-call lines at t=0
    if ((t & (NBUF - 1)) == 0) {
      __syncthreads();
      if (tid < 64)
        __builtin_amdgcn_fence(__ATOMIC_ACQUIRE, "agent");
      __syncthreads();
    }

    // wait only for THIS wave's 32 producer blocks
    wait_group(flags, wave, lane, (unsigned)(t + 1));

    // stage x_{t+1} early: completes under the MFMAs.
    // tid<128 = waves 0,1 — the same waves that read xLds in phase E, so
    // write(t) vs read(t-1) is ordered within-wave; no cross-wave hazard.
    if (t + 1 < ROLLS && tid < 128) {
      int r = tid >> 3, f = tid & 7;
      if (f < F_INPUT)
        xLds[r * 8 + f] = X[(size_t)(t + 1) * N_NODES * F_INPUT +
                            (size_t)(row0 + r) * F_INPUT + f];
    }

    // ---- phase A: issue all 32 Mt loads in ROTATED chunk order (cross-
    // block L3 dedup), then the MFMA chain. areg[s] already matches. ----
    fx4 acc0 = {0.f, 0.f, 0.f, 0.f}, acc1 = {0.f, 0.f, 0.f, 0.f};
    {
      const unsigned short* B0 = m0 + (size_t)l15 * N_NODES + wave * 512 + quad * 8;
      const unsigned short* B1 = B0 + (size_t)16 * N_NODES;
      bf16x8 b0s[16], b1s[16];
#pragma unroll
      for (int s = 0; s < 16; ++s) {
        int kkr = (s + rot) & 15;
        b0s[s] = *(const bf16x8*)(B0 + kkr * 32);
        b1s[s] = *(const bf16x8*)(B1 + kkr * 32);
      }
      __builtin_amdgcn_sched_barrier(0);   // keep all loads issued first
#pragma unroll
      for (int s = 0; s < 16; ++s) {
        acc0 = __builtin_amdgcn_mfma_f32_16x16x32_bf16(areg[s], b0s[s], acc0, 0, 0, 0);
        acc1 = __builtin_amdgcn_mfma_f32_16x16x32_bf16(areg[s], b1s[s], acc1, 0, 0, 0);
      }
    }
#pragma unroll
    for (int r = 0; r < 4; ++r) {
      red[(wave * 16 + quad * 4 + r) * 33 + l15]      = acc0[r];
      red[(wave * 16 + quad * 4 + r) * 33 + 16 + l15] = acc1[r];
    }
    __syncthreads();

    // ---- phase B: reduce 8 partials -> inp bf16 ----
    {
      int m = tid >> 5, n = tid & 31;
      float s = 0.f;
#pragma unroll
      for (int w = 0; w < 8; ++w) s += red[(w * 16 + m) * 33 + n];
      inpB[m * 48 + n] = f2bf(s);
    }
    __syncthreads();

    // ---- phase C: gates(16x128) = inp@Wih^T + h@Whh^T + b ----
    {
      bf16x8 aI = *(const bf16x8*)(inpB + l15 * 48 + quad * 8);
      bf16x8 aH = *(const bf16x8*)(hB   + l15 * 48 + quad * 8);
      fx4 gacc = {0.f, 0.f, 0.f, 0.f};
      gacc = __builtin_amdgcn_mfma_f32_16x16x32_bf16(aI, bI, gacc, 0, 0, 0);
      gacc = __builtin_amdgcn_mfma_f32_16x16x32_bf16(aH, bH, gacc, 0, 0, 0);
#pragma unroll
      for (int r = 0; r < 4; ++r) gatesLds[(quad * 4 + r) * 132 + g] = gacc[r] + bias;
    }
    __syncthreads();

    // ---- phase D: LSTM cell elementwise (fp32 state in LDS) ----
    {
      int r = tid >> 5, k = tid & 31;
      float gi = gatesLds[r * 132 + k];
      float gf = gatesLds[r * 132 + 32 + k];
      float gg = gatesLds[r * 132 + 64 + k];
      float go = gatesLds[r * 132 + 96 + k];
      float i_ = 1.f / (1.f + __expf(-gi));
      float f_ = 1.f / (1.f + __expf(-gf));
      float g_ = tanhf(gg);
      float o_ = 1.f / (1.f + __expf(-go));
      float cn = f_ * cB[r * 32 + k] + i_ * g_;
      float hn = o_ * tanhf(cn);
      cB[r * 32 + k] = cn;
      hB[r * 48 + k] = f2bf(hn);        // next step's h fragment
      cnB[r * 48 + k] = f2bf(cn);
      if (t == ROLLS - 1) gatesLds[r * 132 + k] = hn * Wfc[k];
    }
    __syncthreads();

    // ---- phase E: M_next = h@Wh + c@Wc + x@Wx (waves 0,1) ----
    if (t < ROLLS - 1) {
      if (wave < 2) {
        bf16x8 aH = *(const bf16x8*)(hB  + l15 * 48 + quad * 8);
        bf16x8 aC = *(const bf16x8*)(cnB + l15 * 48 + quad * 8);
        fx4 m4 = {0.f, 0.f, 0.f, 0.f};
        m4 = __builtin_amdgcn_mfma_f32_16x16x32_bf16(aH, bWh, m4, 0, 0, 0);
        m4 = __builtin_amdgcn_mfma_f32_16x16x32_bf16(aC, bWc, m4, 0, 0, 0);
#pragma unroll
        for (int r = 0; r < 4; ++r) {
          int m = quad * 4 + r;
          float xs = m4[r];
#pragma unroll
          for (int f = 0; f < F_INPUT; ++f) xs += xLds[m * 8 + f] * wx5[f];
          MnB[m * 48 + g] = f2bf(xs);
        }
      }
      __syncthreads();                 // MnB ready — waves 1-7 fall through to t+1
      if (wave == 0) {                 // publish tail: 1 KB store + drain + flag
        int k = lane >> 1, half = lane & 1;
        unsigned* dst = (unsigned*)(m1 + (size_t)k * N_NODES + row0) + half * 4;
#pragma unroll
        for (int j = 0; j < 4; ++j) {
          unsigned lo = MnB[(half * 8 + 2 * j) * 48 + k];
          unsigned hi = MnB[(half * 8 + 2 * j + 1) * 48 + k];
          __hip_atomic_store(dst + j, lo | (hi << 16), __ATOMIC_RELAXED,
                             __HIP_MEMORY_SCOPE_AGENT);
        }
        asm volatile("s_waitcnt vmcnt(0)" ::: "memory");
        if (lane == 0)
          __hip_atomic_store(&flags[bid], (unsigned)(t + 2), __ATOMIC_RELAXED,
                             __HIP_MEMORY_SCOPE_AGENT);
      }
    }
  }

  // ---- epilogue: out = h_final @ Wfc^T + b_fc ----
  if (tid < 16) {
    float s = b_fc[0];
#pragma unroll
    for (int k = 0; k < 32; ++k) s += gatesLds[tid * 132 + k];
    out[row0 + tid] = s;
  }
}

extern "C" void kernel_launch(void* const* d_in, const int* in_sizes, int n_in,
                              void* d_out, int out_size, void* d_ws, size_t ws_size,
                              hipStream_t stream) {
  (void)in_sizes; (void)n_in; (void)out_size; (void)ws_size;
  const float* X   = (const float*)d_in[0];
  const float* A   = (const float*)d_in[1];
  const float* Wx  = (const float*)d_in[2];
  const float* Wh  = (const float*)d_in[3];
  const float* Wc  = (const float*)d_in[4];
  const float* Wih = (const float*)d_in[5];
  const float* Whh = (const float*)d_in[6];
  const float* bih = (const float*)d_in[7];
  const float* bhh = (const float*)d_in[8];
  const float* Wfc = (const float*)d_in[9];
  const float* bfc = (const float*)d_in[10];
  float* outp = (float*)d_out;

  char* ws = (char*)d_ws;
  unsigned short* bufs = (unsigned short*)ws;
  ws += (size_t)NBUF * MT_ELEMS * 2;           // 16 MiB Mt ring
  unsigned* flags = (unsigned*)ws;
  ws += NBLK * sizeof(unsigned);

  // epoch flags must start at 0 every call (graph-capturable async memset)
  (void)hipMemsetAsync(flags, 0, NBLK * sizeof(unsigned), stream);

  void* args[] = {
    (void*)&A, (void*)&X, (void*)&Wx, (void*)&Wh, (void*)&Wc,
    (void*)&Wih, (void*)&Whh, (void*)&bih, (void*)&bhh,
    (void*)&Wfc, (void*)&bfc, (void*)&outp,
    (void*)&bufs, (void*)&flags
  };
  (void)hipLaunchCooperativeKernel((const void*)k_roll, dim3(NBLK), dim3(512),
                                   args, 0, stream);
}

// Round 8
// 1750.684 us; speedup vs baseline: 1.4982x; 1.4891x over previous
//
#include <hip/hip_runtime.h>

#define N_NODES 4096
#define H_DIM 32
#define F_INPUT 5
#define ROLLS 200
#define NBLK 256
#define NBUF 64                          // Mt ring: write-once per 64 steps
#define MT_ELEMS ((size_t)H_DIM * N_NODES)   // 131072 shorts = 256 KiB

typedef __attribute__((ext_vector_type(8))) short bf16x8;
typedef __attribute__((ext_vector_type(4))) float fx4;

__device__ __forceinline__ unsigned short f2bf(float f) {
  unsigned int u = __builtin_bit_cast(unsigned int, f);
  u += 0x7fffu + ((u >> 16) & 1u);   // round-to-nearest-even (inputs are benign, no NaN/inf)
  return (unsigned short)(u >> 16);
}

// Single-poller barrier: wave 0 polls all 256 block flags (4/lane,
// agent-scope = L2-bypassing loads); waves 1-7 park at the syncthreads.
// 8x less poll traffic to the L3 flag lines than all-wave polling.
__device__ __forceinline__ void wait_all(const unsigned* flags, int tid,
                                         unsigned target) {
  if (tid < 64) {
    for (;;) {
      bool ok = true;
#pragma unroll
      for (int j = 0; j < 4; ++j) {
        unsigned v = __hip_atomic_load(&flags[tid * 4 + j], __ATOMIC_RELAXED,
                                       __HIP_MEMORY_SCOPE_AGENT);
        ok = ok && (v >= target);
      }
      if (__ballot(ok) == ~0ull) break;
      __builtin_amdgcn_s_sleep(1);
    }
  }
  __syncthreads();
  asm volatile("" ::: "memory");   // keep Mt loads below the wait
}

// Block-major Mt publish: this block's 1 KB tile [h=0..31][16 nodes] is
// CONTIGUOUS at mtblk — wave 0's 64 lanes x 16 B cover it as 16 full 64B
// lines (no partial-line RMW write-through). lane l covers shorts
// [l*8, l*8+8) = h=(l>>1), rows (l&1)*8..+7 of the A-frag-layout tile.
__device__ __forceinline__ void store_mt_block(unsigned short* mtblk,
                                               const unsigned short* tile,
                                               int lane) {
  int h = lane >> 1, half = lane & 1;
  unsigned* dst = (unsigned*)mtblk + lane * 4;
#pragma unroll
  for (int j = 0; j < 4; ++j) {
    unsigned lo = tile[(half * 8 + 2 * j) * 48 + h];
    unsigned hi = tile[(half * 8 + 2 * j + 1) * 48 + h];
    __hip_atomic_store(dst + j, lo | (hi << 16), __ATOMIC_RELAXED,
                       __HIP_MEMORY_SCOPE_AGENT);
  }
}

// Persistent cooperative kernel. grid = 256 blocks (1/CU), 512 threads
// (8 waves), 16 rows/block. A in VGPRs; h/c in LDS; Mt ring (64) in
// global, block-major layout: buffer + pb*512 + h*16 + node_within_pb.
__global__ __launch_bounds__(512, 2) void k_roll(
    const float* __restrict__ A, const float* __restrict__ X,
    const float* __restrict__ Wx, const float* __restrict__ Wh, const float* __restrict__ Wc,
    const float* __restrict__ Wih, const float* __restrict__ Whh,
    const float* __restrict__ b_ih, const float* __restrict__ b_hh,
    const float* __restrict__ Wfc, const float* __restrict__ b_fc,
    float* __restrict__ out,
    unsigned short* __restrict__ bufs, unsigned* __restrict__ flags) {

  __shared__ __align__(16) float red[8 * 16 * 33];          // split-K partials (pad 33)
  __shared__ __align__(16) unsigned short inpB[16 * 48];    // inp bf16, A-frag layout
  __shared__ __align__(16) unsigned short hB[16 * 48];      // persistent h (bf16 frag)
  __shared__ __align__(16) unsigned short cnB[16 * 48];     // c_new bf16 (for M_next)
  __shared__ __align__(16) unsigned short MnB[16 * 48];
  __shared__ __align__(16) float cB[16 * 32];               // persistent c (fp32)
  __shared__ __align__(16) float gatesLds[16 * 132];
  __shared__ __align__(16) float xLds[16 * 8];

  const int tid  = threadIdx.x;
  const int wave = tid >> 6;        // 0..7
  const int lane = tid & 63;
  const int l15  = lane & 15;
  const int quad = lane >> 4;       // 0..3
  const int bid  = blockIdx.x;
  const int row0 = bid << 4;

  // ---- prologue: A fragments fp32->bf16 into VGPRs (once) ----
  bf16x8 areg[16];
  {
    const float* Ap = A + (size_t)(row0 + l15) * N_NODES + wave * 512 + quad * 8;
#pragma unroll
    for (int kk = 0; kk < 16; ++kk) {
      bf16x8 a;
#pragma unroll
      for (int j = 0; j < 8; ++j) a[j] = (short)f2bf(Ap[kk * 32 + j]);
      areg[kk] = a;
    }
  }

  // gate weight fragments: wave w owns gate cols [16w, 16w+16)
  const int g = (wave << 4) + l15;
  bf16x8 bI, bH;
#pragma unroll
  for (int j = 0; j < 8; ++j) {
    bI[j] = (short)f2bf(Wih[g * 32 + quad * 8 + j]);
    bH[j] = (short)f2bf(Whh[g * 32 + quad * 8 + j]);
  }
  const float bias = b_ih[g] + b_hh[g];

  // M_next weight fragments (waves 0,1 only): WhT[n][k]=Wh[k][n]
  bf16x8 bWh, bWc;
  float wx5[F_INPUT];
  if (wave < 2) {
#pragma unroll
    for (int j = 0; j < 8; ++j) {
      bWh[j] = (short)f2bf(Wh[(quad * 8 + j) * H_DIM + g]);
      bWc[j] = (short)f2bf(Wc[(quad * 8 + j) * H_DIM + g]);
    }
#pragma unroll
    for (int f = 0; f < F_INPUT; ++f) wx5[f] = Wx[f * H_DIM + g];
  }

  // h = c = 0 ; Mt0 = (x0 @ Wx)^T staged in LDS
  {
    int r = tid >> 5, k = tid & 31;
    hB[r * 48 + k] = 0;       // f2bf(0)==0
    cB[r * 32 + k] = 0.f;
    float s = 0.f;
#pragma unroll
    for (int f = 0; f < F_INPUT; ++f)
      s += X[(size_t)(row0 + r) * F_INPUT + f] * Wx[f * H_DIM + k];
    MnB[r * 48 + k] = f2bf(s);
  }
  __syncthreads();
  if (wave == 0) {             // store Mt0 (1 KB contiguous) + publish epoch 1
    store_mt_block(bufs + (size_t)bid * 512, MnB, lane);
    asm volatile("s_waitcnt vmcnt(0)" ::: "memory");
    if (lane == 0)
      __hip_atomic_store(&flags[bid], 1u, __ATOMIC_RELAXED,
                         __HIP_MEMORY_SCOPE_AGENT);
  }

  for (int t = 0; t < ROLLS; ++t) {
    const unsigned short* m0 = bufs + (size_t)(t & (NBUF - 1)) * MT_ELEMS;
    unsigned short* m1 = bufs + (size_t)((t + 1) & (NBUF - 1)) * MT_ELEMS;

    // window wrap (t = 0,64,128,192): invalidate L1/L2 once so reused ring
    // buffers can't serve stale lines; also clears prior-call lines at t=0
    if ((t & (NBUF - 1)) == 0) {
      __syncthreads();
      if (tid < 64)
        __builtin_amdgcn_fence(__ATOMIC_ACQUIRE, "agent");
      __syncthreads();
    }

    // wave 0 polls all 256 producer flags; everyone else parks at barrier
    wait_all(flags, tid, (unsigned)(t + 1));

    // stage x_{t+1} early: completes under the MFMAs.
    // tid<128 = waves 0,1 — same waves read xLds in phase E (in-wave order)
    if (t + 1 < ROLLS && tid < 128) {
      int r = tid >> 3, f = tid & 7;
      if (f < F_INPUT)
        xLds[r * 8 + f] = X[(size_t)(t + 1) * N_NODES * F_INPUT +
                            (size_t)(row0 + r) * F_INPUT + f];
    }

    // ---- phase A: issue all 32 Mt loads (block-major addressing), then
    // the MFMA chain. Wave w, subtile s: producer block pb = w*32+s*2+
    // (quad>>1); b0 = [pb][h=l15][(quad&1)*8..+7], b1 = [pb][16+l15][...].
    fx4 acc0 = {0.f, 0.f, 0.f, 0.f}, acc1 = {0.f, 0.f, 0.f, 0.f};
    {
      const unsigned short* Bb = m0 + ((wave << 5) + (quad >> 1)) * 512
                                    + l15 * 16 + (quad & 1) * 8;
      bf16x8 b0s[16], b1s[16];
#pragma unroll
      for (int s = 0; s < 16; ++s) {
        b0s[s] = *(const bf16x8*)(Bb + s * 1024);
        b1s[s] = *(const bf16x8*)(Bb + s * 1024 + 256);
      }
      __builtin_amdgcn_sched_barrier(0);   // keep all loads issued first
#pragma unroll
      for (int s = 0; s < 16; ++s) {
        acc0 = __builtin_amdgcn_mfma_f32_16x16x32_bf16(areg[s], b0s[s], acc0, 0, 0, 0);
        acc1 = __builtin_amdgcn_mfma_f32_16x16x32_bf16(areg[s], b1s[s], acc1, 0, 0, 0);
      }
    }
#pragma unroll
    for (int r = 0; r < 4; ++r) {
      red[(wave * 16 + quad * 4 + r) * 33 + l15]      = acc0[r];
      red[(wave * 16 + quad * 4 + r) * 33 + 16 + l15] = acc1[r];
    }
    __syncthreads();

    // ---- phase B: reduce 8 partials -> inp bf16 ----
    {
      int m = tid >> 5, n = tid & 31;
      float s = 0.f;
#pragma unroll
      for (int w = 0; w < 8; ++w) s += red[(w * 16 + m) * 33 + n];
      inpB[m * 48 + n] = f2bf(s);
    }
    __syncthreads();

    // ---- phase C: gates(16x128) = inp@Wih^T + h@Whh^T + b ----
    {
      bf16x8 aI = *(const bf16x8*)(inpB + l15 * 48 + quad * 8);
      bf16x8 aH = *(const bf16x8*)(hB   + l15 * 48 + quad * 8);
      fx4 gacc = {0.f, 0.f, 0.f, 0.f};
      gacc = __builtin_amdgcn_mfma_f32_16x16x32_bf16(aI, bI, gacc, 0, 0, 0);
      gacc = __builtin_amdgcn_mfma_f32_16x16x32_bf16(aH, bH, gacc, 0, 0, 0);
#pragma unroll
      for (int r = 0; r < 4; ++r) gatesLds[(quad * 4 + r) * 132 + g] = gacc[r] + bias;
    }
    __syncthreads();

    // ---- phase D: LSTM cell elementwise (fp32 state in LDS) ----
    {
      int r = tid >> 5, k = tid & 31;
      float gi = gatesLds[r * 132 + k];
      float gf = gatesLds[r * 132 + 32 + k];
      float gg = gatesLds[r * 132 + 64 + k];
      float go = gatesLds[r * 132 + 96 + k];
      float i_ = 1.f / (1.f + __expf(-gi));
      float f_ = 1.f / (1.f + __expf(-gf));
      float g_ = tanhf(gg);
      float o_ = 1.f / (1.f + __expf(-go));
      float cn = f_ * cB[r * 32 + k] + i_ * g_;
      float hn = o_ * tanhf(cn);
      cB[r * 32 + k] = cn;
      hB[r * 48 + k] = f2bf(hn);        // next step's h fragment
      cnB[r * 48 + k] = f2bf(cn);
      if (t == ROLLS - 1) gatesLds[r * 132 + k] = hn * Wfc[k];
    }
    __syncthreads();

    // ---- phase E: M_next = h@Wh + c@Wc + x@Wx (waves 0,1) ----
    if (t < ROLLS - 1) {
      if (wave < 2) {
        bf16x8 aH = *(const bf16x8*)(hB  + l15 * 48 + quad * 8);
        bf16x8 aC = *(const bf16x8*)(cnB + l15 * 48 + quad * 8);
        fx4 m4 = {0.f, 0.f, 0.f, 0.f};
        m4 = __builtin_amdgcn_mfma_f32_16x16x32_bf16(aH, bWh, m4, 0, 0, 0);
        m4 = __builtin_amdgcn_mfma_f32_16x16x32_bf16(aC, bWc, m4, 0, 0, 0);
#pragma unroll
        for (int r = 0; r < 4; ++r) {
          int m = quad * 4 + r;
          float xs = m4[r];
#pragma unroll
          for (int f = 0; f < F_INPUT; ++f) xs += xLds[m * 8 + f] * wx5[f];
          MnB[m * 48 + g] = f2bf(xs);
        }
      }
      __syncthreads();                 // MnB ready — waves 1-7 fall through
      if (wave == 0) {                 // publish: 1 KB contiguous + drain + flag
        store_mt_block(m1 + (size_t)bid * 512, MnB, lane);
        asm volatile("s_waitcnt vmcnt(0)" ::: "memory");
        if (lane == 0)
          __hip_atomic_store(&flags[bid], (unsigned)(t + 2), __ATOMIC_RELAXED,
                             __HIP_MEMORY_SCOPE_AGENT);
      }
    }
  }

  // ---- epilogue: out = h_final @ Wfc^T + b_fc ----
  if (tid < 16) {
    float s = b_fc[0];
#pragma unroll
    for (int k = 0; k < 32; ++k) s += gatesLds[tid * 132 + k];
    out[row0 + tid] = s;
  }
}

extern "C" void kernel_launch(void* const* d_in, const int* in_sizes, int n_in,
                              void* d_out, int out_size, void* d_ws, size_t ws_size,
                              hipStream_t stream) {
  (void)in_sizes; (void)n_in; (void)out_size; (void)ws_size;
  const float* X   = (const float*)d_in[0];
  const float* A   = (const float*)d_in[1];
  const float* Wx  = (const float*)d_in[2];
  const float* Wh  = (const float*)d_in[3];
  const float* Wc  = (const float*)d_in[4];
  const float* Wih = (const float*)d_in[5];
  const float* Whh = (const float*)d_in[6];
  const float* bih = (const float*)d_in[7];
  const float* bhh = (const float*)d_in[8];
  const float* Wfc = (const float*)d_in[9];
  const float* bfc = (const float*)d_in[10];
  float* outp = (float*)d_out;

  char* ws = (char*)d_ws;
  unsigned short* bufs = (unsigned short*)ws;
  ws += (size_t)NBUF * MT_ELEMS * 2;           // 16 MiB Mt ring
  unsigned* flags = (unsigned*)ws;
  ws += NBLK * sizeof(unsigned);

  // epoch flags must start at 0 every call (graph-capturable async memset)
  (void)hipMemsetAsync(flags, 0, NBLK * sizeof(unsigned), stream);

  void* args[] = {
    (void*)&A, (void*)&X, (void*)&Wx, (void*)&Wh, (void*)&Wc,
    (void*)&Wih, (void*)&Whh, (void*)&bih, (void*)&bhh,
    (void*)&Wfc, (void*)&bfc, (void*)&outp,
    (void*)&bufs, (void*)&flags
  };
  (void)hipLaunchCooperativeKernel((const void*)k_roll, dim3(NBLK), dim3(512),
                                   args, 0, stream);
}